// Round 1
// baseline (511.236 us; speedup 1.0000x reference)
//
#include <hip/hip_runtime.h>
#include <stdint.h>

typedef unsigned short u16;
typedef __attribute__((ext_vector_type(8))) short  s8b;   // 8 bf16 (4 VGPRs)
typedef __attribute__((ext_vector_type(4))) float  f32x4;

#define S_LEN   2048
#define NHEAD   16
#define HD      128
#define DM      2048
#define NB      2
#define NPLANE  (NB*NHEAD)          // 32
#define ROWS    (NB*S_LEN)          // 4096 = M for all GEMMs
#define PLANE_ELEMS (S_LEN*HD)      // 262144
#define ATT_SCALE 0.08838834764831845f   // 1/sqrt(128)

__device__ __forceinline__ float bf2f(u16 u){
  union { unsigned u; float f; } x; x.u = ((unsigned)u) << 16; return x.f;
}
__device__ __forceinline__ u16 f2bf(float f){
  union { float f; unsigned u; } x; x.f = f;
  unsigned r = x.u + 0x7FFFu + ((x.u >> 16) & 1u);   // RNE
  return (u16)(r >> 16);
}

typedef const __attribute__((address_space(1))) unsigned int* gas1;
typedef __attribute__((address_space(3))) unsigned int* las3;
__device__ __forceinline__ void gload16(const void* g, void* l){
  // async global->LDS, dest = wave-uniform base + lane*16
  __builtin_amdgcn_global_load_lds((gas1)g, (las3)l, 16, 0, 0);
}

__device__ __forceinline__ f32x4 mfma16(s8b a, s8b b, f32x4 c){
  return __builtin_amdgcn_mfma_f32_16x16x32_bf16(a, b, c, 0, 0, 0);
}

// ---------------- elementwise f32 -> bf16 (4/thread) ----------------
__global__ __launch_bounds__(256) void cvt4(const float4* __restrict__ in,
                                            uint2* __restrict__ out, int n4){
  int i = blockIdx.x*256 + threadIdx.x;
  if (i >= n4) return;
  float4 v = in[i];
  uint2 o;
  o.x = (unsigned)f2bf(v.x) | ((unsigned)f2bf(v.y) << 16);
  o.y = (unsigned)f2bf(v.z) | ((unsigned)f2bf(v.w) << 16);
  out[i] = o;
}

// ---------------- tiled transpose + convert: in[z][R][C] f32 -> out[z][C][outStride] bf16 ----
__global__ __launch_bounds__(256) void transpose_cvt(const float* __restrict__ in,
                                                     u16* __restrict__ out,
                                                     int R, int C, int outStride){
  __shared__ float tile[32][33];
  int z = blockIdx.z;
  const float* inz = in + (size_t)z * R * C;
  u16* outz = out + (size_t)z * C * outStride;
  int r0 = blockIdx.x*32, c0 = blockIdx.y*32;
  int tx = threadIdx.x, ty = threadIdx.y;   // (32,8)
  #pragma unroll
  for (int i=0;i<4;i++)
    tile[ty*4+i][tx] = inz[(size_t)(r0+ty*4+i)*C + c0 + tx];
  __syncthreads();
  #pragma unroll
  for (int i=0;i<4;i++)
    outz[(size_t)(c0+ty*4+i)*outStride + r0 + tx] = f2bf(tile[tx][ty*4+i]);
}

// ---------------- RoPE table (double precision) ----------------
__global__ __launch_bounds__(256) void rope_tab(float* __restrict__ ctab,
                                                float* __restrict__ stab){
  int i = blockIdx.x*256 + threadIdx.x;   // S_LEN*64
  int p = i >> 6, j = i & 63;
  double freq = pow(10000.0, -(double)j / 64.0);
  double a = (double)p * freq;
  ctab[i] = (float)cos(a);
  stab[i] = (float)sin(a);
}

// ---------------- GEMM: A[4096][2048] bf16 x BT[2048][2048] bf16 (B^T layout) ------------
// mode 0: out bf16 plain (B,H,S,F)      (q_raw / k_raw)
// mode 1: out bf16 V^T tiled+swizzled   (v_t: per plane, tiles of [128 f][64 p])
// mode 2: out f32 [4096][2048] + bias   (final output)
__global__ __launch_bounds__(256) void gemm_bt(const u16* __restrict__ A,
                                               const u16* __restrict__ BT,
                                               const float* __restrict__ bias,
                                               void* __restrict__ out, int mode){
  const int K = 2048;
  __shared__ u16 As[2][4096];   // [128 m][32 k]
  __shared__ u16 Bs[2][4096];   // [128 n][32 k]
  const int t = threadIdx.x, w = t >> 6, l = t & 63;
  const int lr = l & 15, lg = l >> 4;
  const int M0 = blockIdx.y * 128, N0 = blockIdx.x * 128;
  const int wr = w >> 1, wc = w & 1;     // wave 64x64 quadrant

  f32x4 acc[4][4];
  #pragma unroll
  for (int i=0;i<4;i++)
    #pragma unroll
    for (int j=0;j<4;j++) acc[i][j] = f32x4{0.f,0.f,0.f,0.f};

  auto stage = [&](int buf, int kt){
    #pragma unroll
    for (int c=0;c<2;c++){
      int mloc = c*64 + w*16 + (l>>2);
      int kloc = (l&3)*8;
      gload16(A  + (size_t)(M0+mloc)*K + kt*32 + kloc, &As[buf][c*2048 + w*512]);
      gload16(BT + (size_t)(N0+mloc)*K + kt*32 + kloc, &Bs[buf][c*2048 + w*512]);
    }
  };

  stage(0, 0);
  int cur = 0;
  const int NT = K/32;
  for (int kt=0; kt<NT; kt++){
    __syncthreads();                       // staging of cur complete; prev reads drained
    if (kt+1 < NT) stage(cur^1, kt+1);
    s8b af[4], bf[4];
    #pragma unroll
    for (int i=0;i<4;i++){
      af[i] = *(const s8b*)&As[cur][(wr*64 + i*16 + lr)*32 + lg*8];
      bf[i] = *(const s8b*)&Bs[cur][(wc*64 + i*16 + lr)*32 + lg*8];
    }
    #pragma unroll
    for (int i=0;i<4;i++)
      #pragma unroll
      for (int j=0;j<4;j++)
        acc[i][j] = mfma16(af[i], bf[j], acc[i][j]);
    cur ^= 1;
  }

  // epilogue: D layout col=lane&15, row=(lane>>4)*4+reg
  #pragma unroll
  for (int i=0;i<4;i++){
    int growb = M0 + wr*64 + i*16 + lg*4;
    #pragma unroll
    for (int j=0;j<4;j++){
      int gcol = N0 + wc*64 + j*16 + lr;
      float bv = bias[gcol];
      #pragma unroll
      for (int r=0;r<4;r++){
        int grow = growb + r;
        float v = acc[i][j][r] + bv;
        if (mode == 2){
          ((float*)out)[(size_t)grow*2048 + gcol] = v;
        } else {
          int b = grow >> 11, p = grow & 2047;
          int h = gcol >> 7,  f = gcol & 127;
          if (mode == 0){
            ((u16*)out)[(((size_t)(b*NHEAD+h))*S_LEN + p)*HD + f] = f2bf(v);
          } else {
            size_t base = ((size_t)(b*NHEAD+h)*PLANE_ELEMS + (size_t)(p>>6)*8192) * 2;
            int byte = (f*128 + (p&63)*2) ^ ((f&7)<<4);     // V^T tile swizzle
            *(u16*)((char*)out + base + byte) = f2bf(v);
          }
        }
      }
    }
  }
}

// ---------------- RMSNorm + RoPE: one wave per row of 128 ----------------
// swizzled=0: write plain (B,H,S,F). swizzled=1: write K tiled+swizzled ([64 kv][128 f] tiles)
__global__ __launch_bounds__(256) void norm_rope(const u16* __restrict__ in,
                                                 u16* __restrict__ outp,
                                                 const float* __restrict__ nw,
                                                 const float* __restrict__ ctab,
                                                 const float* __restrict__ stab,
                                                 int swizzled){
  int t = threadIdx.x, w = t>>6, l = t&63;
  size_t R = (size_t)blockIdx.x*4 + w;     // over B*H*S rows
  int p = (int)(R & (S_LEN-1));
  size_t base = R * HD;
  float x0 = bf2f(in[base + l]);
  float x1 = bf2f(in[base + 64 + l]);
  float ss = x0*x0 + x1*x1;
  #pragma unroll
  for (int m=1;m<64;m<<=1) ss += __shfl_xor(ss, m);
  float rms = sqrtf(ss * (1.0f/128.0f));
  float sc = 1.0f / (rms + 1e-6f);
  float xn0 = x0 * sc * nw[l];
  float xn1 = x1 * sc * nw[64+l];
  float c = ctab[(size_t)p*64 + l], s = stab[(size_t)p*64 + l];
  float o0 = xn0*c - xn1*s;
  float o1 = xn1*c + xn0*s;
  if (!swizzled){
    outp[base + l]      = f2bf(o0);
    outp[base + 64 + l] = f2bf(o1);
  } else {
    size_t plane = R >> 11;
    int kv = p & 63;
    size_t tb = (plane*(size_t)PLANE_ELEMS + (size_t)(p>>6)*8192) * 2;
    int b0 = (kv*256 + l*2)        ^ ((kv&7)<<4);
    int b1 = (kv*256 + (64+l)*2)   ^ ((kv&7)<<4);
    *(u16*)((char*)outp + tb + b0) = f2bf(o0);
    *(u16*)((char*)outp + tb + b1) = f2bf(o1);
  }
}

// ---------------- flash attention: 4 waves, QBLK=64 (16 rows/wave), KVBLK=64 ----------------
__global__ __launch_bounds__(256) void attn_fwd(const u16* __restrict__ qn,   // plain BHSF
                                                const u16* __restrict__ kn,   // tiled swizzled
                                                const u16* __restrict__ vt,   // V^T tiled swizzled
                                                u16* __restrict__ attn_out){  // (B,S,H,F)
  __shared__ u16 Klds[8192];        // [64 kv][128 f] swizzled
  __shared__ u16 Vlds[8192];        // [128 f][64 kv] swizzled
  __shared__ u16 Plds[4][1152];     // per wave [16 q][72]
  int t = threadIdx.x, w = t>>6, l = t&63;
  int lr = l&15, lg = l>>4;
  int plane = blockIdx.y;
  int q0 = blockIdx.x*64 + w*16;

  s8b qf[4];
  #pragma unroll
  for (int fc=0; fc<4; fc++)
    qf[fc] = *(const s8b*)(qn + ((size_t)plane*S_LEN + q0 + lr)*HD + fc*32 + lg*8);

  float m[4], lsum[4];
  #pragma unroll
  for (int r=0;r<4;r++){ m[r] = -1e30f; lsum[r] = 0.f; }
  f32x4 oacc[8];
  #pragma unroll
  for (int i=0;i<8;i++) oacc[i] = f32x4{0.f,0.f,0.f,0.f};

  const u16* kbase = kn + (size_t)plane*PLANE_ELEMS;
  const u16* vbase = vt + (size_t)plane*PLANE_ELEMS;

  for (int kt=0; kt<32; kt++){
    __syncthreads();                              // prev tile reads done
    #pragma unroll
    for (int i=0;i<4;i++){
      gload16(kbase + (size_t)kt*8192 + w*2048 + i*512 + l*8, &Klds[w*2048 + i*512]);
      gload16(vbase + (size_t)kt*8192 + w*2048 + i*512 + l*8, &Vlds[w*2048 + i*512]);
    }
    __syncthreads();                              // staging complete

    // QK^T: S[q=lg*4+r][kv=c*16+lr]
    f32x4 sacc[4];
    #pragma unroll
    for (int c=0;c<4;c++) sacc[c] = f32x4{0.f,0.f,0.f,0.f};
    #pragma unroll
    for (int c=0;c<4;c++){
      int kv = c*16 + lr;
      #pragma unroll
      for (int fc=0; fc<4; fc++){
        int byte = (kv*256 + (fc*32 + lg*8)*2) ^ ((kv&7)<<4);
        s8b kf = *(const s8b*)((const char*)Klds + byte);
        sacc[c] = mfma16(qf[fc], kf, sacc[c]);
      }
    }

    // online softmax (per q-row, 16-lane groups hold one row set)
    float pv[4][4], alpha[4];
    #pragma unroll
    for (int r=0;r<4;r++){
      float mx = -1e30f;
      #pragma unroll
      for (int c=0;c<4;c++){ float lv = sacc[c][r]*ATT_SCALE; pv[c][r] = lv; mx = fmaxf(mx, lv); }
      #pragma unroll
      for (int mm=1; mm<16; mm<<=1) mx = fmaxf(mx, __shfl_xor(mx, mm));
      float mn = fmaxf(m[r], mx);
      alpha[r] = __expf(m[r] - mn);
      float rs = 0.f;
      #pragma unroll
      for (int c=0;c<4;c++){ float e = __expf(pv[c][r] - mn); pv[c][r] = e; rs += e; }
      #pragma unroll
      for (int mm=1; mm<16; mm<<=1) rs += __shfl_xor(rs, mm);
      lsum[r] = lsum[r]*alpha[r] + rs;
      m[r] = mn;
    }

    // P -> LDS (bf16), layout [q][kv] padded stride 72
    #pragma unroll
    for (int r=0;r<4;r++)
      #pragma unroll
      for (int c=0;c<4;c++)
        Plds[w][(lg*4 + r)*72 + c*16 + lr] = f2bf(pv[c][r]);

    // rescale O
    #pragma unroll
    for (int i=0;i<8;i++)
      #pragma unroll
      for (int r=0;r<4;r++) oacc[i][r] *= alpha[r];

    // PV: O[q][f] += P[q][kv] * V[kv][f]
    #pragma unroll
    for (int kc=0;kc<2;kc++){
      s8b pa = *(const s8b*)&Plds[w][lr*72 + kc*32 + lg*8];
      #pragma unroll
      for (int fc2=0; fc2<8; fc2++){
        int f = fc2*16 + lr;
        int byte = (f*128 + (kc*32 + lg*8)*2) ^ ((f&7)<<4);
        s8b vf = *(const s8b*)((const char*)Vlds + byte);
        oacc[fc2] = mfma16(pa, vf, oacc[fc2]);
      }
    }
  }

  int b = plane >> 4, h = plane & 15;
  #pragma unroll
  for (int fc2=0; fc2<8; fc2++){
    int f = fc2*16 + lr;
    #pragma unroll
    for (int r=0;r<4;r++){
      int row = q0 + lg*4 + r;
      float v = oacc[fc2][r] / lsum[r];
      attn_out[(((size_t)b*S_LEN + row)*NHEAD + h)*HD + f] = f2bf(v);
    }
  }
}

// ---------------------------------------------------------------------------
extern "C" void kernel_launch(void* const* d_in, const int* in_sizes, int n_in,
                              void* d_out, int out_size, void* d_ws, size_t ws_size,
                              hipStream_t stream){
  const float* xq = (const float*)d_in[0];
  const float* xk = (const float*)d_in[1];
  const float* xv = (const float*)d_in[2];
  const float* WQ = (const float*)d_in[3];
  const float* WK = (const float*)d_in[4];
  const float* WV = (const float*)d_in[5];
  const float* WO = (const float*)d_in[6];
  const float* bQ = (const float*)d_in[7];
  const float* bK = (const float*)d_in[8];
  const float* bV = (const float*)d_in[9];
  const float* bO = (const float*)d_in[10];
  const float* qw = (const float*)d_in[11];
  const float* kw = (const float*)d_in[12];

  char* ws = (char*)d_ws;
  size_t off = 0;
  auto alloc = [&](size_t bytes)->void*{
    void* p = ws + off; off += (bytes + 255) & ~(size_t)255; return p;
  };
  const size_t ACT = (size_t)ROWS*DM*2;    // 16.78 MB (bf16 [4096][2048])
  const size_t WMT = (size_t)DM*DM*2;      // 8.39 MB
  u16* xqb  = (u16*)alloc(ACT);
  u16* xkb  = (u16*)alloc(ACT);
  u16* xvb  = (u16*)alloc(ACT);
  u16* WqT  = (u16*)alloc(WMT);
  u16* WkT  = (u16*)alloc(WMT);
  u16* WvT  = (u16*)alloc(WMT);
  u16* WoT  = (u16*)alloc(WMT);
  u16* qraw = (u16*)alloc(ACT);
  u16* kraw = (u16*)alloc(ACT);
  u16* knT  = (u16*)alloc(ACT);
  u16* vtS  = (u16*)alloc(ACT);
  u16* attn = (u16*)alloc(ACT);
  float* ctab = (float*)alloc((size_t)S_LEN*64*4);
  float* stab = (float*)alloc((size_t)S_LEN*64*4);
  if (off > ws_size) return;               // ws too small -> absmax will flag it

  const int n4 = ROWS*DM/4;                // 2097152
  cvt4<<<dim3(n4/256), dim3(256), 0, stream>>>((const float4*)xq, (uint2*)xqb, n4);
  cvt4<<<dim3(n4/256), dim3(256), 0, stream>>>((const float4*)xk, (uint2*)xkb, n4);
  cvt4<<<dim3(n4/256), dim3(256), 0, stream>>>((const float4*)xv, (uint2*)xvb, n4);
  rope_tab<<<dim3(S_LEN*64/256), dim3(256), 0, stream>>>(ctab, stab);
  // W_Q/K/V: (H,D,F) -> [h*128+f][d]
  transpose_cvt<<<dim3(64,4,16), dim3(32,8), 0, stream>>>(WQ, WqT, 2048, 128, 2048);
  transpose_cvt<<<dim3(64,4,16), dim3(32,8), 0, stream>>>(WK, WkT, 2048, 128, 2048);
  transpose_cvt<<<dim3(64,4,16), dim3(32,8), 0, stream>>>(WV, WvT, 2048, 128, 2048);
  // W_O: [hf][m] -> [m][hf]
  transpose_cvt<<<dim3(64,64,1), dim3(32,8), 0, stream>>>(WO, WoT, 2048, 2048, 2048);

  gemm_bt<<<dim3(16,32), dim3(256), 0, stream>>>(xqb, WqT, bQ, qraw, 0);
  gemm_bt<<<dim3(16,32), dim3(256), 0, stream>>>(xkb, WkT, bK, kraw, 0);
  gemm_bt<<<dim3(16,32), dim3(256), 0, stream>>>(xvb, WvT, bV, vtS, 1);

  norm_rope<<<dim3(NPLANE*S_LEN/4), dim3(256), 0, stream>>>(qraw, qraw, qw, ctab, stab, 0);
  norm_rope<<<dim3(NPLANE*S_LEN/4), dim3(256), 0, stream>>>(kraw, knT, kw, ctab, stab, 1);

  attn_fwd<<<dim3(S_LEN/64, NPLANE), dim3(256), 0, stream>>>(qraw, knT, vtS, attn);

  gemm_bt<<<dim3(16,32), dim3(256), 0, stream>>>(attn, WoT, bO, d_out, 2);
}

// Round 2
// 466.052 us; speedup vs baseline: 1.0969x; 1.0969x over previous
//
#include <hip/hip_runtime.h>
#include <stdint.h>

typedef unsigned short u16;
typedef __attribute__((ext_vector_type(8))) short  s8b;   // 8 bf16 (4 VGPRs)
typedef __attribute__((ext_vector_type(4))) float  f32x4;

#define S_LEN   2048
#define NHEAD   16
#define HD      128
#define DM      2048
#define NB      2
#define NPLANE  (NB*NHEAD)          // 32
#define ROWS    (NB*S_LEN)          // 4096 = M for all GEMMs
#define PLANE_ELEMS (S_LEN*HD)      // 262144
#define ATT_SCALE 0.08838834764831845f   // 1/sqrt(128)

__device__ __forceinline__ float bf2f(u16 u){
  union { unsigned u; float f; } x; x.u = ((unsigned)u) << 16; return x.f;
}
__device__ __forceinline__ u16 f2bf(float f){
  union { float f; unsigned u; } x; x.f = f;
  unsigned r = x.u + 0x7FFFu + ((x.u >> 16) & 1u);   // RNE
  return (u16)(r >> 16);
}

typedef const __attribute__((address_space(1))) unsigned int* gas1;
typedef __attribute__((address_space(3))) unsigned int* las3;
__device__ __forceinline__ void gload16(const void* g, void* l){
  // async global->LDS, dest = wave-uniform base + lane*16
  __builtin_amdgcn_global_load_lds((gas1)g, (las3)l, 16, 0, 0);
}

__device__ __forceinline__ f32x4 mfma16(s8b a, s8b b, f32x4 c){
  return __builtin_amdgcn_mfma_f32_16x16x32_bf16(a, b, c, 0, 0, 0);
}

// ---------------- elementwise f32 -> bf16 (4/thread) ----------------
__global__ __launch_bounds__(256) void cvt4(const float4* __restrict__ in,
                                            uint2* __restrict__ out, int n4){
  int i = blockIdx.x*256 + threadIdx.x;
  if (i >= n4) return;
  float4 v = in[i];
  uint2 o;
  o.x = (unsigned)f2bf(v.x) | ((unsigned)f2bf(v.y) << 16);
  o.y = (unsigned)f2bf(v.z) | ((unsigned)f2bf(v.w) << 16);
  out[i] = o;
}

// ---------------- tiled transpose + convert: in[z][R][C] f32 -> out[z][C][outStride] bf16 ----
__global__ __launch_bounds__(256) void transpose_cvt(const float* __restrict__ in,
                                                     u16* __restrict__ out,
                                                     int R, int C, int outStride){
  __shared__ float tile[32][33];
  int z = blockIdx.z;
  const float* inz = in + (size_t)z * R * C;
  u16* outz = out + (size_t)z * C * outStride;
  int r0 = blockIdx.x*32, c0 = blockIdx.y*32;
  int tx = threadIdx.x, ty = threadIdx.y;   // (32,8)
  #pragma unroll
  for (int i=0;i<4;i++)
    tile[ty*4+i][tx] = inz[(size_t)(r0+ty*4+i)*C + c0 + tx];
  __syncthreads();
  #pragma unroll
  for (int i=0;i<4;i++)
    outz[(size_t)(c0+ty*4+i)*outStride + r0 + tx] = f2bf(tile[tx][ty*4+i]);
}

// ---------------- RoPE table (double precision) ----------------
__global__ __launch_bounds__(256) void rope_tab(float* __restrict__ ctab,
                                                float* __restrict__ stab){
  int i = blockIdx.x*256 + threadIdx.x;   // S_LEN*64
  int p = i >> 6, j = i & 63;
  double freq = pow(10000.0, -(double)j / 64.0);
  double a = (double)p * freq;
  ctab[i] = (float)cos(a);
  stab[i] = (float)sin(a);
}

// ---------------- GEMM: A[4096][2048] bf16 x BT[2048][2048] bf16 (B^T layout) ------------
// mode 0: out bf16 plain (B,H,S,F)      (q_raw / k_raw)
// mode 1: out bf16 V^T tiled+swizzled   (v_t: per plane, tiles of [128 f][64 p])
// mode 2: out f32 [4096][2048] + bias   (final output)
__global__ __launch_bounds__(256) void gemm_bt(const u16* __restrict__ A,
                                               const u16* __restrict__ BT,
                                               const float* __restrict__ bias,
                                               void* __restrict__ out, int mode){
  const int K = 2048;
  __shared__ u16 As[2][4096];   // [128 m][32 k]
  __shared__ u16 Bs[2][4096];   // [128 n][32 k]
  const int t = threadIdx.x, w = t >> 6, l = t & 63;
  const int lr = l & 15, lg = l >> 4;
  const int M0 = blockIdx.y * 128, N0 = blockIdx.x * 128;
  const int wr = w >> 1, wc = w & 1;     // wave 64x64 quadrant

  f32x4 acc[4][4];
  #pragma unroll
  for (int i=0;i<4;i++)
    #pragma unroll
    for (int j=0;j<4;j++) acc[i][j] = f32x4{0.f,0.f,0.f,0.f};

  auto stage = [&](int buf, int kt){
    #pragma unroll
    for (int c=0;c<2;c++){
      int mloc = c*64 + w*16 + (l>>2);
      int kloc = (l&3)*8;
      gload16(A  + (size_t)(M0+mloc)*K + kt*32 + kloc, &As[buf][c*2048 + w*512]);
      gload16(BT + (size_t)(N0+mloc)*K + kt*32 + kloc, &Bs[buf][c*2048 + w*512]);
    }
  };

  stage(0, 0);
  int cur = 0;
  const int NT = K/32;
  for (int kt=0; kt<NT; kt++){
    __syncthreads();                       // staging of cur complete; prev reads drained
    if (kt+1 < NT) stage(cur^1, kt+1);
    s8b af[4], bf[4];
    #pragma unroll
    for (int i=0;i<4;i++){
      af[i] = *(const s8b*)&As[cur][(wr*64 + i*16 + lr)*32 + lg*8];
      bf[i] = *(const s8b*)&Bs[cur][(wc*64 + i*16 + lr)*32 + lg*8];
    }
    __builtin_amdgcn_s_setprio(1);
    #pragma unroll
    for (int i=0;i<4;i++)
      #pragma unroll
      for (int j=0;j<4;j++)
        acc[i][j] = mfma16(af[i], bf[j], acc[i][j]);
    __builtin_amdgcn_s_setprio(0);
    cur ^= 1;
  }

  // epilogue: D layout col=lane&15, row=(lane>>4)*4+reg
  #pragma unroll
  for (int i=0;i<4;i++){
    int growb = M0 + wr*64 + i*16 + lg*4;
    #pragma unroll
    for (int j=0;j<4;j++){
      int gcol = N0 + wc*64 + j*16 + lr;
      float bv = bias[gcol];
      #pragma unroll
      for (int r=0;r<4;r++){
        int grow = growb + r;
        float v = acc[i][j][r] + bv;
        if (mode == 2){
          ((float*)out)[(size_t)grow*2048 + gcol] = v;
        } else {
          int b = grow >> 11, p = grow & 2047;
          int h = gcol >> 7,  f = gcol & 127;
          if (mode == 0){
            ((u16*)out)[(((size_t)(b*NHEAD+h))*S_LEN + p)*HD + f] = f2bf(v);
          } else {
            size_t base = ((size_t)(b*NHEAD+h)*PLANE_ELEMS + (size_t)(p>>6)*8192) * 2;
            int byte = (f*128 + (p&63)*2) ^ ((f&7)<<4);     // V^T tile swizzle
            *(u16*)((char*)out + base + byte) = f2bf(v);
          }
        }
      }
    }
  }
}

// ---------------- RMSNorm + RoPE: one wave per row of 128 ----------------
// swizzled=0: write plain (B,H,S,F), scaled by oscale. swizzled=1: write K tiled+swizzled
__global__ __launch_bounds__(256) void norm_rope(const u16* __restrict__ in,
                                                 u16* __restrict__ outp,
                                                 const float* __restrict__ nw,
                                                 const float* __restrict__ ctab,
                                                 const float* __restrict__ stab,
                                                 int swizzled, float oscale){
  int t = threadIdx.x, w = t>>6, l = t&63;
  size_t R = (size_t)blockIdx.x*4 + w;     // over B*H*S rows
  int p = (int)(R & (S_LEN-1));
  size_t base = R * HD;
  float x0 = bf2f(in[base + l]);
  float x1 = bf2f(in[base + 64 + l]);
  float ss = x0*x0 + x1*x1;
  #pragma unroll
  for (int m=1;m<64;m<<=1) ss += __shfl_xor(ss, m);
  float rms = sqrtf(ss * (1.0f/128.0f));
  float sc = oscale / (rms + 1e-6f);
  float xn0 = x0 * sc * nw[l];
  float xn1 = x1 * sc * nw[64+l];
  float c = ctab[(size_t)p*64 + l], s = stab[(size_t)p*64 + l];
  float o0 = xn0*c - xn1*s;
  float o1 = xn1*c + xn0*s;
  if (!swizzled){
    outp[base + l]      = f2bf(o0);
    outp[base + 64 + l] = f2bf(o1);
  } else {
    size_t plane = R >> 11;
    int kv = p & 63;
    size_t tb = (plane*(size_t)PLANE_ELEMS + (size_t)(p>>6)*8192) * 2;
    int b0 = (kv*256 + l*2)        ^ ((kv&7)<<4);
    int b1 = (kv*256 + (64+l)*2)   ^ ((kv&7)<<4);
    *(u16*)((char*)outp + tb + b0) = f2bf(o0);
    *(u16*)((char*)outp + tb + b1) = f2bf(o1);
  }
}

// ---------------- flash attention: 4 waves, QBLK=64 (16 rows/wave), KVBLK=64 ----------------
// double-buffered K/V staging (2-phase), defer-max softmax, XCD-pinned planes
__global__ __launch_bounds__(256) void attn_fwd(const u16* __restrict__ qn,   // plain BHSF (prescaled)
                                                const u16* __restrict__ kn,   // tiled swizzled
                                                const u16* __restrict__ vt,   // V^T tiled swizzled
                                                u16* __restrict__ attn_out){  // (B,S,H,F)
  __shared__ u16 Klds[2][8192];     // [64 kv][128 f] swizzled
  __shared__ u16 Vlds[2][8192];     // [128 f][64 kv] swizzled
  __shared__ u16 Plds[4][1152];     // per wave [16 q][72], XOR bit5^q3
  int t = threadIdx.x, w = t>>6, l = t&63;
  int lr = l&15, lg = l>>4;

  // XCD-aware decomposition: plane pinned to one XCD (bid&7)
  int bid = blockIdx.x;                  // 0..1023
  int xcd = bid & 7, j = bid >> 3;       // j 0..127
  int plane = xcd*4 + (j >> 5);          // 4 planes per XCD
  int qb = j & 31;
  int q0 = qb*64 + w*16;

  s8b qf[4];
  #pragma unroll
  for (int fc=0; fc<4; fc++)
    qf[fc] = *(const s8b*)(qn + ((size_t)plane*S_LEN + q0 + lr)*HD + fc*32 + lg*8);

  float m[4], lsum[4];
  #pragma unroll
  for (int r=0;r<4;r++){ m[r] = -1e30f; lsum[r] = 0.f; }
  f32x4 oacc[8];
  #pragma unroll
  for (int i=0;i<8;i++) oacc[i] = f32x4{0.f,0.f,0.f,0.f};

  const u16* kbase = kn + (size_t)plane*PLANE_ELEMS;
  const u16* vbase = vt + (size_t)plane*PLANE_ELEMS;

  auto stage = [&](int buf, int kt){
    #pragma unroll
    for (int i=0;i<4;i++){
      gload16(kbase + (size_t)kt*8192 + w*2048 + i*512 + l*8, &Klds[buf][w*2048 + i*512]);
      gload16(vbase + (size_t)kt*8192 + w*2048 + i*512 + l*8, &Vlds[buf][w*2048 + i*512]);
    }
  };

  stage(0, 0);
  int cur = 0;
  for (int kt=0; kt<32; kt++){
    __syncthreads();                    // buf[cur] staged (vmcnt drained); buf[cur^1] reads done
    if (kt+1 < 32) stage(cur^1, kt+1);  // async loads fly under compute

    // QK^T: S[q=lg*4+r][kv=c*16+lr]  (scale folded into Q)
    f32x4 sacc[4];
    #pragma unroll
    for (int c=0;c<4;c++) sacc[c] = f32x4{0.f,0.f,0.f,0.f};
    __builtin_amdgcn_s_setprio(1);
    #pragma unroll
    for (int c=0;c<4;c++){
      int kv = c*16 + lr;
      #pragma unroll
      for (int fc=0; fc<4; fc++){
        int byte = (kv*256 + (fc*32 + lg*8)*2) ^ ((kv&7)<<4);
        s8b kf = *(const s8b*)((const char*)&Klds[cur][0] + byte);
        sacc[c] = mfma16(qf[fc], kf, sacc[c]);
      }
    }
    __builtin_amdgcn_s_setprio(0);

    // online softmax with defer-max (THR=8)
    float mx[4];
    #pragma unroll
    for (int r=0;r<4;r++){
      float v = fmaxf(fmaxf(sacc[0][r], sacc[1][r]), fmaxf(sacc[2][r], sacc[3][r]));
      #pragma unroll
      for (int mm=1; mm<16; mm<<=1) v = fmaxf(v, __shfl_xor(v, mm));
      mx[r] = v;
    }
    bool need = false;
    #pragma unroll
    for (int r=0;r<4;r++) need |= (mx[r] > m[r] + 8.f);
    if (__any(need)){
      #pragma unroll
      for (int r=0;r<4;r++){
        float mn = fmaxf(m[r], mx[r]);
        float al = __expf(m[r] - mn);
        lsum[r] *= al; m[r] = mn;
        #pragma unroll
        for (int i=0;i<8;i++) oacc[i][r] *= al;
      }
    }
    float pv[4][4];
    #pragma unroll
    for (int r=0;r<4;r++){
      float rs = 0.f;
      #pragma unroll
      for (int c=0;c<4;c++){ float e = __expf(sacc[c][r] - m[r]); pv[c][r] = e; rs += e; }
      #pragma unroll
      for (int mm=1; mm<16; mm<<=1) rs += __shfl_xor(rs, mm);
      lsum[r] += rs;
    }

    // P -> LDS bf16, [q][72] with byte ^= (q&8)<<2 (conflict-free writes)
    #pragma unroll
    for (int r=0;r<4;r++){
      int q = lg*4 + r;
      #pragma unroll
      for (int c=0;c<4;c++){
        int byte = (q*144 + (c*16 + lr)*2) ^ ((q&8)<<2);
        *(u16*)((char*)&Plds[w][0] + byte) = f2bf(pv[c][r]);
      }
    }

    // PV: O[q][f] += P[q][kv] * V[kv][f]
    __builtin_amdgcn_s_setprio(1);
    #pragma unroll
    for (int kc=0;kc<2;kc++){
      int pbyte = (lr*144 + (kc*32 + lg*8)*2) ^ ((lr&8)<<2);
      s8b pa = *(const s8b*)((const char*)&Plds[w][0] + pbyte);
      #pragma unroll
      for (int fc2=0; fc2<8; fc2++){
        int f = fc2*16 + lr;
        int byte = (f*128 + (kc*32 + lg*8)*2) ^ ((f&7)<<4);
        s8b vf = *(const s8b*)((const char*)&Vlds[cur][0] + byte);
        oacc[fc2] = mfma16(pa, vf, oacc[fc2]);
      }
    }
    __builtin_amdgcn_s_setprio(0);
    cur ^= 1;
  }

  int b = plane >> 4, h = plane & 15;
  #pragma unroll
  for (int fc2=0; fc2<8; fc2++){
    int f = fc2*16 + lr;
    #pragma unroll
    for (int r=0;r<4;r++){
      int row = q0 + lg*4 + r;
      float v = oacc[fc2][r] / lsum[r];
      attn_out[(((size_t)b*S_LEN + row)*NHEAD + h)*HD + f] = f2bf(v);
    }
  }
}

// ---------------------------------------------------------------------------
extern "C" void kernel_launch(void* const* d_in, const int* in_sizes, int n_in,
                              void* d_out, int out_size, void* d_ws, size_t ws_size,
                              hipStream_t stream){
  const float* xq = (const float*)d_in[0];
  const float* xk = (const float*)d_in[1];
  const float* xv = (const float*)d_in[2];
  const float* WQ = (const float*)d_in[3];
  const float* WK = (const float*)d_in[4];
  const float* WV = (const float*)d_in[5];
  const float* WO = (const float*)d_in[6];
  const float* bQ = (const float*)d_in[7];
  const float* bK = (const float*)d_in[8];
  const float* bV = (const float*)d_in[9];
  const float* bO = (const float*)d_in[10];
  const float* qw = (const float*)d_in[11];
  const float* kw = (const float*)d_in[12];

  char* ws = (char*)d_ws;
  size_t off = 0;
  auto alloc = [&](size_t bytes)->void*{
    void* p = ws + off; off += (bytes + 255) & ~(size_t)255; return p;
  };
  const size_t ACT = (size_t)ROWS*DM*2;    // 16.78 MB (bf16 [4096][2048])
  const size_t WMT = (size_t)DM*DM*2;      // 8.39 MB
  u16* xqb  = (u16*)alloc(ACT);
  u16* xkb  = (u16*)alloc(ACT);
  u16* xvb  = (u16*)alloc(ACT);
  u16* WqT  = (u16*)alloc(WMT);
  u16* WkT  = (u16*)alloc(WMT);
  u16* WvT  = (u16*)alloc(WMT);
  u16* WoT  = (u16*)alloc(WMT);
  u16* qraw = (u16*)alloc(ACT);
  u16* kraw = (u16*)alloc(ACT);
  u16* knT  = (u16*)alloc(ACT);
  u16* vtS  = (u16*)alloc(ACT);
  u16* attn = (u16*)alloc(ACT);
  float* ctab = (float*)alloc((size_t)S_LEN*64*4);
  float* stab = (float*)alloc((size_t)S_LEN*64*4);
  if (off > ws_size) return;               // ws too small -> absmax will flag it

  const int n4 = ROWS*DM/4;                // 2097152
  cvt4<<<dim3(n4/256), dim3(256), 0, stream>>>((const float4*)xq, (uint2*)xqb, n4);
  cvt4<<<dim3(n4/256), dim3(256), 0, stream>>>((const float4*)xk, (uint2*)xkb, n4);
  cvt4<<<dim3(n4/256), dim3(256), 0, stream>>>((const float4*)xv, (uint2*)xvb, n4);
  rope_tab<<<dim3(S_LEN*64/256), dim3(256), 0, stream>>>(ctab, stab);
  // W_Q/K/V: (H,D,F) -> [h*128+f][d]
  transpose_cvt<<<dim3(64,4,16), dim3(32,8), 0, stream>>>(WQ, WqT, 2048, 128, 2048);
  transpose_cvt<<<dim3(64,4,16), dim3(32,8), 0, stream>>>(WK, WkT, 2048, 128, 2048);
  transpose_cvt<<<dim3(64,4,16), dim3(32,8), 0, stream>>>(WV, WvT, 2048, 128, 2048);
  // W_O: [hf][m] -> [m][hf]
  transpose_cvt<<<dim3(64,64,1), dim3(32,8), 0, stream>>>(WO, WoT, 2048, 2048, 2048);

  gemm_bt<<<dim3(16,32), dim3(256), 0, stream>>>(xqb, WqT, bQ, qraw, 0);
  gemm_bt<<<dim3(16,32), dim3(256), 0, stream>>>(xkb, WkT, bK, kraw, 0);
  gemm_bt<<<dim3(16,32), dim3(256), 0, stream>>>(xvb, WvT, bV, vtS, 1);

  norm_rope<<<dim3(NPLANE*S_LEN/4), dim3(256), 0, stream>>>(qraw, qraw, qw, ctab, stab, 0, ATT_SCALE);
  norm_rope<<<dim3(NPLANE*S_LEN/4), dim3(256), 0, stream>>>(kraw, knT, kw, ctab, stab, 1, 1.0f);

  attn_fwd<<<dim3(1024), dim3(256), 0, stream>>>(qraw, knT, vtS, attn);

  gemm_bt<<<dim3(16,32), dim3(256), 0, stream>>>(attn, WoT, bO, d_out, 2);
}

// Round 3
// 421.618 us; speedup vs baseline: 1.2126x; 1.1054x over previous
//
#include <hip/hip_runtime.h>
#include <stdint.h>

typedef unsigned short u16;
typedef __attribute__((ext_vector_type(8))) short  s8b;   // 8 bf16 (4 VGPRs)
typedef __attribute__((ext_vector_type(4))) float  f32x4;

#define S_LEN   2048
#define NHEAD   16
#define HD      128
#define DM      2048
#define NB      2
#define NPLANE  (NB*NHEAD)          // 32
#define ROWS    (NB*S_LEN)          // 4096 = M for all GEMMs
#define PLANE_ELEMS (S_LEN*HD)      // 262144
#define ATT_SCALE 0.08838834764831845f   // 1/sqrt(128)

__device__ __forceinline__ float bf2f(u16 u){
  union { unsigned u; float f; } x; x.u = ((unsigned)u) << 16; return x.f;
}
__device__ __forceinline__ u16 f2bf(float f){
  union { float f; unsigned u; } x; x.f = f;
  unsigned r = x.u + 0x7FFFu + ((x.u >> 16) & 1u);   // RNE
  return (u16)(r >> 16);
}

typedef const __attribute__((address_space(1))) unsigned int* gas1;
typedef __attribute__((address_space(3))) unsigned int* las3;
__device__ __forceinline__ void gload16(const void* g, void* l){
  // async global->LDS, dest = wave-uniform base + lane*16
  __builtin_amdgcn_global_load_lds((gas1)g, (las3)l, 16, 0, 0);
}

__device__ __forceinline__ f32x4 mfma16(s8b a, s8b b, f32x4 c){
  return __builtin_amdgcn_mfma_f32_16x16x32_bf16(a, b, c, 0, 0, 0);
}

// ---------------- elementwise f32 -> bf16 (4/thread) ----------------
__global__ __launch_bounds__(256) void cvt4(const float4* __restrict__ in,
                                            uint2* __restrict__ out, int n4){
  int i = blockIdx.x*256 + threadIdx.x;
  if (i >= n4) return;
  float4 v = in[i];
  uint2 o;
  o.x = (unsigned)f2bf(v.x) | ((unsigned)f2bf(v.y) << 16);
  o.y = (unsigned)f2bf(v.z) | ((unsigned)f2bf(v.w) << 16);
  out[i] = o;
}

// ---------------- tiled transpose + convert: in[z][R][C] f32 -> out[z][C][outStride] bf16 ----
__global__ __launch_bounds__(256) void transpose_cvt(const float* __restrict__ in,
                                                     u16* __restrict__ out,
                                                     int R, int C, int outStride){
  __shared__ float tile[32][33];
  int z = blockIdx.z;
  const float* inz = in + (size_t)z * R * C;
  u16* outz = out + (size_t)z * C * outStride;
  int r0 = blockIdx.x*32, c0 = blockIdx.y*32;
  int tx = threadIdx.x, ty = threadIdx.y;   // (32,8)
  #pragma unroll
  for (int i=0;i<4;i++)
    tile[ty*4+i][tx] = inz[(size_t)(r0+ty*4+i)*C + c0 + tx];
  __syncthreads();
  #pragma unroll
  for (int i=0;i<4;i++)
    outz[(size_t)(c0+ty*4+i)*outStride + r0 + tx] = f2bf(tile[tx][ty*4+i]);
}

// ---------------- RoPE table (double precision) ----------------
__global__ __launch_bounds__(256) void rope_tab(float* __restrict__ ctab,
                                                float* __restrict__ stab){
  int i = blockIdx.x*256 + threadIdx.x;   // S_LEN*64
  int p = i >> 6, j = i & 63;
  double freq = pow(10000.0, -(double)j / 64.0);
  double a = (double)p * freq;
  ctab[i] = (float)cos(a);
  stab[i] = (float)sin(a);
}

// ---------------- GEMM: A[4096][2048] bf16 x BT[2048][2048] bf16 (B^T layout) ------------
// grid: 1D 512 (16 N-tiles x 32 M-tiles), XCD-swizzled
// mode 0: out bf16 plain (B,H,S,F)      (q_raw / k_raw)
// mode 1: out bf16 V^T tiled+swizzled   (v_t: per plane, tiles of [128 f][64 p])
// mode 2: out f32 [4096][2048] + bias   (final output)
__global__ __launch_bounds__(256) void gemm_bt(const u16* __restrict__ A,
                                               const u16* __restrict__ BT,
                                               const float* __restrict__ bias,
                                               void* __restrict__ out, int mode){
  const int K = 2048;
  __shared__ u16 As[2][4096];   // [128 m][32 k]
  __shared__ u16 Bs[2][4096];   // [128 n][32 k]
  const int t = threadIdx.x, w = t >> 6, l = t & 63;
  const int lr = l & 15, lg = l >> 4;
  // XCD-aware bijective swizzle (512 % 8 == 0)
  int bid = blockIdx.x;
  int swz = (bid & 7)*64 + (bid >> 3);
  const int M0 = (swz >> 4) * 128, N0 = (swz & 15) * 128;
  const int wr = w >> 1, wc = w & 1;     // wave 64x64 quadrant

  f32x4 acc[4][4];
  #pragma unroll
  for (int i=0;i<4;i++)
    #pragma unroll
    for (int j=0;j<4;j++) acc[i][j] = f32x4{0.f,0.f,0.f,0.f};

  auto stage = [&](int buf, int kt){
    #pragma unroll
    for (int c=0;c<2;c++){
      int mloc = c*64 + w*16 + (l>>2);
      int kloc = (l&3)*8;
      gload16(A  + (size_t)(M0+mloc)*K + kt*32 + kloc, &As[buf][c*2048 + w*512]);
      gload16(BT + (size_t)(N0+mloc)*K + kt*32 + kloc, &Bs[buf][c*2048 + w*512]);
    }
  };

  stage(0, 0);
  int cur = 0;
  const int NT = K/32;
  for (int kt=0; kt<NT; kt++){
    __syncthreads();                       // staging of cur complete; prev reads drained
    if (kt+1 < NT) stage(cur^1, kt+1);
    s8b af[4], bf[4];
    #pragma unroll
    for (int i=0;i<4;i++){
      af[i] = *(const s8b*)&As[cur][(wr*64 + i*16 + lr)*32 + lg*8];
      bf[i] = *(const s8b*)&Bs[cur][(wc*64 + i*16 + lr)*32 + lg*8];
    }
    __builtin_amdgcn_s_setprio(1);
    #pragma unroll
    for (int i=0;i<4;i++)
      #pragma unroll
      for (int j=0;j<4;j++)
        acc[i][j] = mfma16(af[i], bf[j], acc[i][j]);
    __builtin_amdgcn_s_setprio(0);
    cur ^= 1;
  }

  // epilogue: D layout col=lane&15, row=(lane>>4)*4+reg
  #pragma unroll
  for (int i=0;i<4;i++){
    int growb = M0 + wr*64 + i*16 + lg*4;
    #pragma unroll
    for (int j=0;j<4;j++){
      int gcol = N0 + wc*64 + j*16 + lr;
      float bv = bias[gcol];
      #pragma unroll
      for (int r=0;r<4;r++){
        int grow = growb + r;
        float v = acc[i][j][r] + bv;
        if (mode == 2){
          ((float*)out)[(size_t)grow*2048 + gcol] = v;
        } else {
          int b = grow >> 11, p = grow & 2047;
          int h = gcol >> 7,  f = gcol & 127;
          if (mode == 0){
            ((u16*)out)[(((size_t)(b*NHEAD+h))*S_LEN + p)*HD + f] = f2bf(v);
          } else {
            size_t base = ((size_t)(b*NHEAD+h)*PLANE_ELEMS + (size_t)(p>>6)*8192) * 2;
            int byte = (f*128 + (p&63)*2) ^ ((f&7)<<4);     // V^T tile swizzle
            *(u16*)((char*)out + base + byte) = f2bf(v);
          }
        }
      }
    }
  }
}

// ---------------- RMSNorm + RoPE: one wave per row of 128 ----------------
// swizzled=0: write plain (B,H,S,F), scaled by oscale. swizzled=1: write K tiled+swizzled
__global__ __launch_bounds__(256) void norm_rope(const u16* __restrict__ in,
                                                 u16* __restrict__ outp,
                                                 const float* __restrict__ nw,
                                                 const float* __restrict__ ctab,
                                                 const float* __restrict__ stab,
                                                 int swizzled, float oscale){
  int t = threadIdx.x, w = t>>6, l = t&63;
  size_t R = (size_t)blockIdx.x*4 + w;     // over B*H*S rows
  int p = (int)(R & (S_LEN-1));
  size_t base = R * HD;
  float x0 = bf2f(in[base + l]);
  float x1 = bf2f(in[base + 64 + l]);
  float ss = x0*x0 + x1*x1;
  #pragma unroll
  for (int m=1;m<64;m<<=1) ss += __shfl_xor(ss, m);
  float rms = sqrtf(ss * (1.0f/128.0f));
  float sc = oscale / (rms + 1e-6f);
  float xn0 = x0 * sc * nw[l];
  float xn1 = x1 * sc * nw[64+l];
  float c = ctab[(size_t)p*64 + l], s = stab[(size_t)p*64 + l];
  float o0 = xn0*c - xn1*s;
  float o1 = xn1*c + xn0*s;
  if (!swizzled){
    outp[base + l]      = f2bf(o0);
    outp[base + 64 + l] = f2bf(o1);
  } else {
    size_t plane = R >> 11;
    int kv = p & 63;
    size_t tb = (plane*(size_t)PLANE_ELEMS + (size_t)(p>>6)*8192) * 2;
    int b0 = (kv*256 + l*2)        ^ ((kv&7)<<4);
    int b1 = (kv*256 + (64+l)*2)   ^ ((kv&7)<<4);
    *(u16*)((char*)outp + tb + b0) = f2bf(o0);
    *(u16*)((char*)outp + tb + b1) = f2bf(o1);
  }
}

// ---------------- flash attention: 8 waves, QBLK=128 (16 rows/wave), KVBLK=64 ----------------
// double-buffered K/V (2-phase), defer-max (no per-tile cross-lane reduce), XCD-pinned planes
__global__ __launch_bounds__(512) void attn_fwd(const u16* __restrict__ qn,   // plain BHSF (prescaled)
                                                const u16* __restrict__ kn,   // tiled swizzled
                                                const u16* __restrict__ vt,   // V^T tiled swizzled
                                                u16* __restrict__ attn_out){  // (B,S,H,F)
  __shared__ u16 Klds[2][8192];     // [64 kv][128 f] swizzled
  __shared__ u16 Vlds[2][8192];     // [128 f][64 kv] swizzled
  __shared__ u16 Plds[8][1024];     // per wave [16 q][64 kv], byte ^= (q>>2)<<5
  int t = threadIdx.x, w = t>>6, l = t&63;
  int lr = l&15, lg = l>>4;

  // XCD-aware decomposition: plane pinned to one XCD (bid&7); 512 blocks, all resident
  int bid = blockIdx.x;                  // 0..511
  int xcd = bid & 7, j = bid >> 3;       // j 0..63
  int plane = xcd*4 + (j >> 4);          // 4 planes per XCD
  int qb = j & 15;
  int q0 = qb*128 + w*16;

  s8b qf[4];
  #pragma unroll
  for (int fc=0; fc<4; fc++)
    qf[fc] = *(const s8b*)(qn + ((size_t)plane*S_LEN + q0 + lr)*HD + fc*32 + lg*8);

  float m[4], lsum[4];                   // lsum = per-lane partial; reduced at end
  #pragma unroll
  for (int r=0;r<4;r++){ m[r] = -1e30f; lsum[r] = 0.f; }
  f32x4 oacc[8];
  #pragma unroll
  for (int i=0;i<8;i++) oacc[i] = f32x4{0.f,0.f,0.f,0.f};

  const u16* kbase = kn + (size_t)plane*PLANE_ELEMS;
  const u16* vbase = vt + (size_t)plane*PLANE_ELEMS;

  auto stage = [&](int buf, int kt){
    #pragma unroll
    for (int i=0;i<2;i++){
      gload16(kbase + (size_t)kt*8192 + w*1024 + i*512 + l*8, &Klds[buf][w*1024 + i*512]);
      gload16(vbase + (size_t)kt*8192 + w*1024 + i*512 + l*8, &Vlds[buf][w*1024 + i*512]);
    }
  };

  stage(0, 0);
  int cur = 0;
  for (int kt=0; kt<32; kt++){
    __syncthreads();                    // buf[cur] staged (vmcnt drained); buf[cur^1] reads done
    if (kt+1 < 32) stage(cur^1, kt+1);  // async loads fly under compute

    // QK^T: S[q=lg*4+r][kv=c*16+lr]  (scale folded into Q)
    f32x4 sacc[4];
    #pragma unroll
    for (int c=0;c<4;c++) sacc[c] = f32x4{0.f,0.f,0.f,0.f};
    __builtin_amdgcn_s_setprio(1);
    #pragma unroll
    for (int c=0;c<4;c++){
      int kv = c*16 + lr;
      #pragma unroll
      for (int fc=0; fc<4; fc++){
        int byte = (kv*256 + (fc*32 + lg*8)*2) ^ ((kv&7)<<4);
        s8b kf = *(const s8b*)((const char*)&Klds[cur][0] + byte);
        sacc[c] = mfma16(qf[fc], kf, sacc[c]);
      }
    }
    __builtin_amdgcn_s_setprio(0);

    // defer-max online softmax: local (in-lane) max check only; rescale is rare
    float mx[4]; bool need = false;
    #pragma unroll
    for (int r=0;r<4;r++){
      mx[r] = fmaxf(fmaxf(sacc[0][r], sacc[1][r]), fmaxf(sacc[2][r], sacc[3][r]));
      need |= (mx[r] > m[r] + 8.f);
    }
    if (__any(need)){
      #pragma unroll
      for (int r=0;r<4;r++){
        float v = mx[r];
        #pragma unroll
        for (int mm=1; mm<16; mm<<=1) v = fmaxf(v, __shfl_xor(v, mm));
        float mn = fmaxf(m[r], v);
        float al = __expf(m[r] - mn);
        lsum[r] *= al; m[r] = mn;
        #pragma unroll
        for (int i=0;i<8;i++) oacc[i][r] *= al;
      }
    }
    float pv[4][4];
    #pragma unroll
    for (int r=0;r<4;r++){
      #pragma unroll
      for (int c=0;c<4;c++){
        float e = __expf(sacc[c][r] - m[r]);
        pv[c][r] = e; lsum[r] += e;      // per-lane partial sum (no shfl)
      }
    }

    // P -> LDS bf16, [16 q][64 kv], byte ^= (q>>2)<<5 (== lg<<5); conflict-free
    #pragma unroll
    for (int r=0;r<4;r++){
      int q = lg*4 + r;
      #pragma unroll
      for (int c=0;c<4;c++){
        int byte = (q*128 + (c*16 + lr)*2) ^ (lg<<5);
        *(u16*)((char*)&Plds[w][0] + byte) = f2bf(pv[c][r]);
      }
    }

    // PV: O[q][f] += P[q][kv] * V[kv][f]
    __builtin_amdgcn_s_setprio(1);
    #pragma unroll
    for (int kc=0;kc<2;kc++){
      int pbyte = (lr*128 + kc*64 + lg*16) ^ ((lr>>2)<<5);
      s8b pa = *(const s8b*)((const char*)&Plds[w][0] + pbyte);
      #pragma unroll
      for (int fc2=0; fc2<8; fc2++){
        int f = fc2*16 + lr;
        int byte = (f*128 + (kc*32 + lg*8)*2) ^ ((f&7)<<4);
        s8b vf = *(const s8b*)((const char*)&Vlds[cur][0] + byte);
        oacc[fc2] = mfma16(pa, vf, oacc[fc2]);
      }
    }
    __builtin_amdgcn_s_setprio(0);
    cur ^= 1;
  }

  // final: reduce lsum across the 16-lane group, then normalize + store
  #pragma unroll
  for (int r=0;r<4;r++){
    float v = lsum[r];
    #pragma unroll
    for (int mm=1; mm<16; mm<<=1) v += __shfl_xor(v, mm);
    lsum[r] = 1.0f / v;
  }
  int b = plane >> 4, h = plane & 15;
  #pragma unroll
  for (int fc2=0; fc2<8; fc2++){
    int f = fc2*16 + lr;
    #pragma unroll
    for (int r=0;r<4;r++){
      int row = q0 + lg*4 + r;
      float v = oacc[fc2][r] * lsum[r];
      attn_out[(((size_t)b*S_LEN + row)*NHEAD + h)*HD + f] = f2bf(v);
    }
  }
}

// ---------------------------------------------------------------------------
extern "C" void kernel_launch(void* const* d_in, const int* in_sizes, int n_in,
                              void* d_out, int out_size, void* d_ws, size_t ws_size,
                              hipStream_t stream){
  const float* xq = (const float*)d_in[0];
  const float* xk = (const float*)d_in[1];
  const float* xv = (const float*)d_in[2];
  const float* WQ = (const float*)d_in[3];
  const float* WK = (const float*)d_in[4];
  const float* WV = (const float*)d_in[5];
  const float* WO = (const float*)d_in[6];
  const float* bQ = (const float*)d_in[7];
  const float* bK = (const float*)d_in[8];
  const float* bV = (const float*)d_in[9];
  const float* bO = (const float*)d_in[10];
  const float* qw = (const float*)d_in[11];
  const float* kw = (const float*)d_in[12];

  char* ws = (char*)d_ws;
  size_t off = 0;
  auto alloc = [&](size_t bytes)->void*{
    void* p = ws + off; off += (bytes + 255) & ~(size_t)255; return p;
  };
  const size_t ACT = (size_t)ROWS*DM*2;    // 16.78 MB (bf16 [4096][2048])
  const size_t WMT = (size_t)DM*DM*2;      // 8.39 MB
  u16* xqb  = (u16*)alloc(ACT);
  u16* xkb  = (u16*)alloc(ACT);
  u16* xvb  = (u16*)alloc(ACT);
  u16* WqT  = (u16*)alloc(WMT);
  u16* WkT  = (u16*)alloc(WMT);
  u16* WvT  = (u16*)alloc(WMT);
  u16* WoT  = (u16*)alloc(WMT);
  u16* qraw = (u16*)alloc(ACT);
  u16* kraw = (u16*)alloc(ACT);
  u16* knT  = (u16*)alloc(ACT);
  u16* vtS  = (u16*)alloc(ACT);
  u16* attn = (u16*)alloc(ACT);
  float* ctab = (float*)alloc((size_t)S_LEN*64*4);
  float* stab = (float*)alloc((size_t)S_LEN*64*4);
  if (off > ws_size) return;               // ws too small -> absmax will flag it

  const int n4 = ROWS*DM/4;                // 2097152
  cvt4<<<dim3(n4/256), dim3(256), 0, stream>>>((const float4*)xq, (uint2*)xqb, n4);
  cvt4<<<dim3(n4/256), dim3(256), 0, stream>>>((const float4*)xk, (uint2*)xkb, n4);
  cvt4<<<dim3(n4/256), dim3(256), 0, stream>>>((const float4*)xv, (uint2*)xvb, n4);
  rope_tab<<<dim3(S_LEN*64/256), dim3(256), 0, stream>>>(ctab, stab);
  // W_Q/K/V: (H,D,F) -> [h*128+f][d]
  transpose_cvt<<<dim3(64,4,16), dim3(32,8), 0, stream>>>(WQ, WqT, 2048, 128, 2048);
  transpose_cvt<<<dim3(64,4,16), dim3(32,8), 0, stream>>>(WK, WkT, 2048, 128, 2048);
  transpose_cvt<<<dim3(64,4,16), dim3(32,8), 0, stream>>>(WV, WvT, 2048, 128, 2048);
  // W_O: [hf][m] -> [m][hf]
  transpose_cvt<<<dim3(64,64,1), dim3(32,8), 0, stream>>>(WO, WoT, 2048, 2048, 2048);

  gemm_bt<<<dim3(512), dim3(256), 0, stream>>>(xqb, WqT, bQ, qraw, 0);
  gemm_bt<<<dim3(512), dim3(256), 0, stream>>>(xkb, WkT, bK, kraw, 0);
  gemm_bt<<<dim3(512), dim3(256), 0, stream>>>(xvb, WvT, bV, vtS, 1);

  norm_rope<<<dim3(NPLANE*S_LEN/4), dim3(256), 0, stream>>>(qraw, qraw, qw, ctab, stab, 0, ATT_SCALE);
  norm_rope<<<dim3(NPLANE*S_LEN/4), dim3(256), 0, stream>>>(kraw, knT, kw, ctab, stab, 1, 1.0f);

  attn_fwd<<<dim3(512), dim3(512), 0, stream>>>(qraw, knT, vtS, attn);

  gemm_bt<<<dim3(512), dim3(256), 0, stream>>>(attn, WoT, bO, d_out, 2);
}